// Round 16
// baseline (233.287 us; speedup 1.0000x reference)
//
#include <hip/hip_runtime.h>
#include <hip/hip_bf16.h>
#include <math.h>

typedef _Float16 f16;
typedef _Float16 f16x8 __attribute__((ext_vector_type(8)));
typedef _Float16 f16x4 __attribute__((ext_vector_type(4)));
typedef _Float16 f16x2 __attribute__((ext_vector_type(2)));
typedef _Float16 half2v __attribute__((ext_vector_type(2)));
typedef float    f32x4 __attribute__((ext_vector_type(4)));

#define NN 1024
#define EE 2048
#define DD 256
#define EDH 128

typedef const __attribute__((address_space(1))) void gas_t;
typedef __attribute__((address_space(3))) void las_t;
#define GLOAD16(g, l) __builtin_amdgcn_global_load_lds((gas_t*)(g), (las_t*)(l), 16, 0, 0)

#if __has_builtin(__builtin_amdgcn_fdot2)
#define DOT2(a, b, c) __builtin_amdgcn_fdot2((a), (b), (c), false)
#else
#define DOT2(a, b, c) ((float)(a)[0]*(float)(b)[0] + (float)(a)[1]*(float)(b)[1] + (c))
#endif

// ---------------- prep: embed (4 nodes/block, +bn stats) fused with edge-MLP ----------------

__global__ __launch_bounds__(256) void k_embed_hidden(const float* __restrict__ x,
    const float* __restrict__ lw, const float* __restrict__ lb,
    const float* __restrict__ ea, const float* __restrict__ w1, const float* __restrict__ b1,
    float* __restrict__ y, float* __restrict__ colsum, float* __restrict__ colsq,
    f16* __restrict__ h16e) {
  int bid = blockIdx.x, t = threadIdx.x;
  if (bid < 256) {
    int n0 = bid*4;
    __shared__ float xr[4][38];
    if (t < 152) ((float*)xr)[t] = x[n0*38 + t];
    __syncthreads();
    float b0 = lb[t];
    float s0 = b0, s1 = b0, s2 = b0, s3 = b0;
    const float* w = lw + t*38;
    #pragma unroll
    for (int d = 0; d < 38; d++) {
      float wd = w[d];
      s0 += xr[0][d]*wd; s1 += xr[1][d]*wd; s2 += xr[2][d]*wd; s3 += xr[3][d]*wd;
    }
    y[(n0+0)*DD + t] = s0; y[(n0+1)*DD + t] = s1;
    y[(n0+2)*DD + t] = s2; y[(n0+3)*DD + t] = s3;
    atomicAdd(&colsum[t], s0+s1+s2+s3);
    atomicAdd(&colsq[t], s0*s0+s1*s1+s2*s2+s3*s3);
  } else {
    int e = (bid - 256)*2 + (t >> 7);
    int k = t & 127;
    const float* a = ea + e*4;
    const float* w = w1 + k*4;
    float s = b1[k] + a[0]*w[0] + a[1]*w[1] + a[2]*w[2] + a[3]*w[3];
    h16e[e*EDH + k] = (f16)(1.f / (1.f + expf(-s)));
  }
}

// ---------------- merged: CSR build (block 0, wave-scan) + bn-normalize (blocks 1..256) --------

__global__ __launch_bounds__(1024) void k_csrbn(const int* __restrict__ ei,
    int* __restrict__ cntAll, int* __restrict__ offAll, float* __restrict__ denomB,
    unsigned* __restrict__ rec, int* __restrict__ srcD,
    const float* __restrict__ y, const float* __restrict__ colsum,
    const float* __restrict__ colsq, const float* __restrict__ g, const float* __restrict__ b,
    float* __restrict__ xh, f16* __restrict__ xc16) {
  int bid = blockIdx.x, t = threadIdx.x;
  if (bid > 0) {                       // bn apply: 256 blocks x 1024 elems
    int i = (bid - 1)*1024 + t;
    int c = i & 255;
    float mean = colsum[c] * (1.f/1024.f);
    float var  = colsq[c] * (1.f/1024.f) - mean*mean;
    float sc = g[c] / sqrtf(var + 1e-5f);
    float sh = b[c] - mean*sc;
    float v = y[i]*sc + sh;
    xh[i] = v;
    xc16[i] = (f16)v;
    return;
  }
  // block 0: CSR build with wave-level scans
  __shared__ int cntD[1024], cntS[1024], curD[1024], curS[1024];
  __shared__ int wsD[16], wsS[16];
  cntD[t] = 0; cntS[t] = 0;
  __syncthreads();
  int e0 = t, e1 = 1024 + t;
  int d0 = ei[EE + e0], s0 = ei[e0];
  int d1 = ei[EE + e1], s1 = ei[e1];
  atomicAdd(&cntD[d0], 1); atomicAdd(&cntS[s0], 1);
  atomicAdd(&cntD[d1], 1); atomicAdd(&cntS[s1], 1);
  __syncthreads();
  int cD = cntD[t], cS = cntS[t];
  int lane = t & 63, wid = t >> 6;
  int iD = cD, iS = cS;                // wave-inclusive scans
  #pragma unroll
  for (int o = 1; o < 64; o <<= 1) {
    int uD = __shfl_up(iD, o, 64);
    int uS = __shfl_up(iS, o, 64);
    if (lane >= o) { iD += uD; iS += uS; }
  }
  if (lane == 63) { wsD[wid] = iD; wsS[wid] = iS; }
  __syncthreads();
  if (t < 16) {
    int vD = wsD[t], vS = wsS[t];
    #pragma unroll
    for (int o = 1; o < 16; o <<= 1) {
      int uD = __shfl_up(vD, o, 64);
      int uS = __shfl_up(vS, o, 64);
      if (t >= o) { vD += uD; vS += uS; }
    }
    wsD[t] = vD; wsS[t] = vS;
  }
  __syncthreads();
  int exD = (wid ? wsD[wid-1] : 0) + iD - cD;
  int exS = (wid ? wsS[wid-1] : 0) + iS - cS;
  curD[t] = exD; curS[t] = exS;
  cntAll[t] = cD; offAll[t] = exD;
  offAll[1024 + t] = exS;
  denomB[t] = (float)(cD > 1 ? cD : 1);
  __syncthreads();
  int pD = atomicAdd(&curD[d0], 1);
  int pS = atomicAdd(&curS[s0], 1);
  rec[pS] = (unsigned)e0 | ((unsigned)s0 << 11) | ((unsigned)pD << 21);
  srcD[pD] = s0;
  pD = atomicAdd(&curD[d1], 1);
  pS = atomicAdd(&curS[s1], 1);
  rec[pS] = (unsigned)e1 | ((unsigned)s1 << 11) | ((unsigned)pD << 21);
  srcD[pD] = s1;
}

// ---------------- merged weight prep: w2 transpose + all casts + Bside build ----------------

__global__ __launch_bounds__(256) void k_prep(const float* __restrict__ w2, f16* __restrict__ BTb,
    const float* __restrict__ s0, f16* __restrict__ d0,
    const float* __restrict__ s1, f16* __restrict__ d1,
    const float* __restrict__ s2, f16* __restrict__ d2,
    const float* __restrict__ s3, f16* __restrict__ d3,
    const float* __restrict__ rw, const float* __restrict__ nb2, f16* __restrict__ Bside) {
  __shared__ __align__(16) char shm[33280];
  int bid = blockIdx.x, t = threadIdx.x;
  if (bid < 512) {                     // w2 transpose
    f16 (*ls)[130] = (f16(*)[130])shm;
    int f = bid & 255, dh = bid >> 8;
    int dl = t >> 1, kh = (t & 1) * 64;
    const float* src = w2 + ((size_t)(dh*128 + dl)*256 + f)*128 + kh;
    #pragma unroll
    for (int i = 0; i < 16; i++) {
      f32x4 v = *(const f32x4*)(src + i*4);
      f16x2 a = {(f16)v[0], (f16)v[1]};
      f16x2 bb = {(f16)v[2], (f16)v[3]};
      *(f16x2*)(&ls[dl][kh + i*4])     = a;
      *(f16x2*)(&ls[dl][kh + i*4 + 2]) = bb;
    }
    __syncthreads();
    int k = t >> 1, dh2 = (t & 1) * 64;
    f16* dst = BTb + ((size_t)f*128 + k)*256 + dh*128 + dh2;
    #pragma unroll
    for (int gq = 0; gq < 8; gq++) {
      f16x8 pk;
      #pragma unroll
      for (int q = 0; q < 8; q++) pk[q] = ls[dh2 + gq*8 + q][k];
      *(f16x8*)(dst + gq*8) = pk;
    }
  } else if (bid < 2176) {             // casts
    int cb = bid - 512;
    const float* src; f16* dst; int i;
    if      (cb < 192)  { src = s0; dst = d0; i = cb*256 + t; }
    else if (cb < 384)  { src = s1; dst = d1; i = (cb-192)*256 + t; }
    else if (cb < 1024) { src = s2; dst = d2; i = (cb-384)*256 + t; }
    else                { src = s3; dst = d3; i = (cb-1024)*256 + t; }
    f32x4 v = ((const f32x4*)src)[i];
    f16x4 r; r[0]=(f16)v[0]; r[1]=(f16)v[1]; r[2]=(f16)v[2]; r[3]=(f16)v[3];
    ((f16x4*)dst)[i] = r;
  } else if (bid < 2240) {             // root linear
    int i = (bid - 2176)*256 + t;
    f32x4 v = *(const f32x4*)(rw + (size_t)i*4);
    f16x4 r; r[0]=(f16)v[0]; r[1]=(f16)v[1]; r[2]=(f16)v[2]; r[3]=(f16)v[3];
    *(f16x4*)(Bside + 65536 + (size_t)i*4) = r;
  } else {                             // b2 transpose
    float (*ls)[65] = (float(*)[65])shm;
    int fb = bid - 2240;
    for (int db = 0; db < 4; db++) {
      int r = t >> 2, cs = (t & 3) * 16;
      const float* s = nb2 + (size_t)(db*64 + r)*256 + fb*64 + cs;
      #pragma unroll
      for (int i = 0; i < 16; i += 4) {
        f32x4 v = *(const f32x4*)(s + i);
        ls[r][cs+i] = v[0]; ls[r][cs+i+1] = v[1]; ls[r][cs+i+2] = v[2]; ls[r][cs+i+3] = v[3];
      }
      __syncthreads();
      int fl = t >> 2, ds2 = (t & 3) * 16;
      f16x8 p0, p1;
      #pragma unroll
      for (int q = 0; q < 8; q++) { p0[q] = (f16)ls[ds2+q][fl]; p1[q] = (f16)ls[ds2+8+q][fl]; }
      f16* d = Bside + (size_t)(fb*64 + fl)*256 + db*64 + ds2;
      *(f16x8*)(d)     = p0;
      *(f16x8*)(d + 8) = p1;
      __syncthreads();
    }
  }
}

// ---------------- fused conv GEMM (64x128 tile, BK=64, high-occupancy) + edge epilogue ---------

__global__ __launch_bounds__(256) void k_fgemm(const f16* __restrict__ A,
    const f16* __restrict__ BTb, const f16* __restrict__ Bside, const f16* __restrict__ Wbh,
    const f16* __restrict__ h16e, const int* __restrict__ offAll,
    const unsigned* __restrict__ rec, float* __restrict__ T2R,
    float* __restrict__ G2, float* __restrict__ msgbuf) {
  __shared__ __align__(16) f16 lds[12288];   // 24KB: As 4096 + Bs 8192; tile 64x128 (8192) aliases
  int raw = blockIdx.x;
  int pmod = raw & 7, q = raw >> 3;
  int m = q & 15, pg = q >> 4;
  int p = pg*8 + pmod;                 // same p%8 -> same XCD
  if (p >= 266) return;
  int m0 = m*64;
  int t = threadIdx.x;
  int lane = t & 63, wv = t >> 6, wm = wv >> 1, wn = wv & 1;
  int lr = lane & 15, lg = lane >> 4;
  const f16* Bbase = (p < 256) ? (BTb + (size_t)p*32768)
                   : (p < 260) ? (Bside + (size_t)(p-256)*32768)
                               : (Wbh + (size_t)(p-260)*32768);
  int ea = wv*512 + lane*8;
  int ra = ea >> 5, ca = ea & 31;
  const f16* AgA = A + (size_t)(m0 + ra)*256 + ca;
  int e0 = wv*1024 + lane*8;
  int r0 = e0 >> 5, c0 = e0 & 31;
  int e1 = e0 + 512;
  int r1 = e1 >> 5, c1 = e1 & 31;
  const f16* Bg0 = Bbase + (size_t)r0*256 + c0;
  const f16* Bg1 = Bbase + (size_t)r1*256 + c1;
  f16* As = lds;
  f16* Bs = lds + 4096;
  f16* AlA = As + wv*512;
  f16* Bl0 = Bs + wv*1024; f16* Bl1 = Bl0 + 512;
  f32x4 acc[2][4] = {};
  for (int k0 = 0; k0 < 256; k0 += 64) {
    __syncthreads();
    GLOAD16(AgA + k0,      AlA);
    GLOAD16(AgA + k0 + 32, AlA + 2048);
    GLOAD16(Bg0 + k0,      Bl0);
    GLOAD16(Bg1 + k0,      Bl1);
    GLOAD16(Bg0 + k0 + 32, Bl0 + 4096);
    GLOAD16(Bg1 + k0 + 32, Bl1 + 4096);
    __syncthreads();
    #pragma unroll
    for (int P = 0; P < 2; P++) {
      f16x8 af[2], bf[4];
      #pragma unroll
      for (int i = 0; i < 2; i++)
        af[i] = *(const f16x8*)(&As[P*2048 + (wm*32 + i*16 + lr)*32 + lg*8]);
      #pragma unroll
      for (int j = 0; j < 4; j++)
        bf[j] = *(const f16x8*)(&Bs[P*4096 + (wn*64 + j*16 + lr)*32 + lg*8]);
      #pragma unroll
      for (int i = 0; i < 2; i++)
        #pragma unroll
        for (int j = 0; j < 4; j++)
          acc[i][j] = __builtin_amdgcn_mfma_f32_16x16x32_f16(af[i], bf[j], acc[i][j], 0, 0, 0);
    }
  }
  if (p >= 260) {
    int c0o = (p - 260)*128;
    #pragma unroll
    for (int i = 0; i < 2; i++)
      #pragma unroll
      for (int j = 0; j < 4; j++)
        #pragma unroll
        for (int v = 0; v < 4; v++)
          G2[(size_t)(m0 + wm*32 + i*16 + lg*4 + v)*768 + c0o + wn*64 + j*16 + lr] = acc[i][j][v];
    return;
  }
  if (p >= 256) {
    int c0o = (p - 256)*128;
    #pragma unroll
    for (int i = 0; i < 2; i++)
      #pragma unroll
      for (int j = 0; j < 4; j++)
        #pragma unroll
        for (int v = 0; v < 4; v++)
          T2R[(size_t)(m0 + wm*32 + i*16 + lg*4 + v)*512 + c0o + wn*64 + j*16 + lr] = acc[i][j][v];
    return;
  }
  __syncthreads();
  #pragma unroll
  for (int i = 0; i < 2; i++)
    #pragma unroll
    for (int j = 0; j < 4; j++)
      #pragma unroll
      for (int v = 0; v < 4; v++) {
        int r = wm*32 + i*16 + lg*4 + v;
        int c = wn*64 + j*16 + lr;
        lds[r*128 + (((c >> 3) ^ (r & 7)) << 3) + (c & 7)] = (f16)acc[i][j][v];
      }
  __syncthreads();
  int eS = offAll[1024 + m0];
  int eE = (m0 + 64 < 1024) ? offAll[1024 + m0 + 64] : EE;
  int g = t & 1, es = t >> 1;
  for (int idx = eS + es; idx < eE; idx += 128) {
    unsigned u = rec[idx];
    int e = u & 2047, src = (u >> 11) & 1023, pos = (int)(u >> 21);
    int r = src - m0;
    const f16* hp = h16e + (size_t)e*EDH + g*64;
    float s0 = 0.f, s1 = 0.f;
    #pragma unroll
    for (int i = 0; i < 8; i++) {
      int blk = g*8 + i;
      f16x8 hv = *(const f16x8*)(hp + i*8);
      f16x8 tv = *(const f16x8*)(&lds[r*128 + ((blk ^ (r & 7)) << 3)]);
      union { f16x8 v8; half2v pr[4]; } hu, tu;
      hu.v8 = hv; tu.v8 = tv;
      float sx = (i & 1) ? s1 : s0;
      #pragma unroll
      for (int qd = 0; qd < 4; qd++) sx = DOT2(hu.pr[qd], tu.pr[qd], sx);
      if (i & 1) s1 = sx; else s0 = sx;
    }
    float s = s0 + s1;
    s += __shfl_xor(s, 1, 64);
    if (g == 0) msgbuf[(size_t)pos*256 + p] = s;
  }
}

// ---------------- fin: segment-sum msgbuf + per-edge b2 term, /denom, +root+bias, relu ----------

__global__ __launch_bounds__(256) void k_fin(const float* __restrict__ msgbuf,
    const int* __restrict__ cntAll, const int* __restrict__ offAll,
    const float* __restrict__ denomB, const float* __restrict__ T2R,
    const int* __restrict__ srcD, const float* __restrict__ cb, f16* __restrict__ Am) {
  int n = blockIdx.x, t = threadIdx.x;
  int deg = cntAll[n], o = offAll[n];
  float s = 0.f;
  for (int j = 0; j < deg; j++)
    s += msgbuf[(size_t)(o+j)*256 + t] + T2R[(size_t)srcD[o+j]*512 + t];
  float m = s / denomB[n] + T2R[(size_t)n*512 + 256 + t] + cb[t];
  Am[(size_t)n*256 + t] = (f16)fmaxf(m, 0.f);
}

// ---------------- fused GRU: gi-GEMM (32x64 tile x 3 gates) + gate epilogue ----------------
// WG computes gi[m0..m0+32][g*256 + n0..n0+64] for g=0..2, then full gate math ->
// hNew (f32) + xc16 (f16). gh read from G2 (written by fgemm).

__global__ __launch_bounds__(256) void k_gru(const f16* __restrict__ Am,
    const f16* __restrict__ Wih, const float* __restrict__ G2,
    const float* __restrict__ bih, const float* __restrict__ bhh,
    const float* __restrict__ hOld, float* __restrict__ hNew, f16* __restrict__ xc16) {
  __shared__ __align__(16) f16 As[32*40];
  __shared__ __align__(16) f16 Bs[3][64*40];
  int t = threadIdx.x;
  int m0 = blockIdx.x*32, n0 = blockIdx.y*64;
  int lane = t & 63, wv = t >> 6, wm = wv >> 1, wn = wv & 1;
  int lr = lane & 15, lg = lane >> 4, lk = lg * 8;
  int brow = t >> 2, bseg = (t & 3) * 8;
  f32x4 acc[3][2] = {};
  for (int k0 = 0; k0 < 256; k0 += 32) {
    __syncthreads();
    if (t < 128)
      *(f16x8*)(&As[brow*40 + bseg]) = *(const f16x8*)(Am + (size_t)(m0 + brow)*256 + k0 + bseg);
    #pragma unroll
    for (int g = 0; g < 3; g++)
      *(f16x8*)(&Bs[g][brow*40 + bseg]) =
          *(const f16x8*)(Wih + (size_t)(g*256 + n0 + brow)*256 + k0 + bseg);
    __syncthreads();
    f16x8 af = *(const f16x8*)(&As[(wm*16 + lr)*40 + lk]);
    #pragma unroll
    for (int g = 0; g < 3; g++) {
      f16x8 b0 = *(const f16x8*)(&Bs[g][(wn*32 + lr)*40 + lk]);
      f16x8 b1 = *(const f16x8*)(&Bs[g][(wn*32 + 16 + lr)*40 + lk]);
      acc[g][0] = __builtin_amdgcn_mfma_f32_16x16x32_f16(af, b0, acc[g][0], 0, 0, 0);
      acc[g][1] = __builtin_amdgcn_mfma_f32_16x16x32_f16(af, b1, acc[g][1], 0, 0, 0);
    }
  }
  #pragma unroll
  for (int j = 0; j < 2; j++)
    #pragma unroll
    for (int v = 0; v < 4; v++) {
      int r = m0 + wm*16 + lg*4 + v;
      int c = n0 + wn*32 + j*16 + lr;
      const float* ghr = G2 + (size_t)r*768;
      float ir  = acc[0][j][v] + bih[c],       hr = ghr[c]       + bhh[c];
      float iz  = acc[1][j][v] + bih[256 + c], hz = ghr[256 + c] + bhh[256 + c];
      float inn = acc[2][j][v] + bih[512 + c], hn = ghr[512 + c] + bhh[512 + c];
      float rg = 1.f / (1.f + expf(-(ir + hr)));
      float zz = 1.f / (1.f + expf(-(iz + hz)));
      float nn = tanhf(inn + rg*hn);
      float hv = (1.f - zz)*nn + zz*hOld[(size_t)r*256 + c];
      hNew[(size_t)r*256 + c] = hv;
      xc16[(size_t)r*256 + c] = (f16)hv;
    }
}

// ---------------- small GEMM: 64x128 tile. MODE 1: f32 store; MODE 3: bias+relu f16 ----------------

template<int MODE>
__global__ __launch_bounds__(256) void k_gemm_sm(const f16* __restrict__ A,
    const f16* __restrict__ BT, float* __restrict__ C, f16* __restrict__ Ch,
    const float* __restrict__ bias, int K, int lda, int ldb, int N,
    int bsA, int bsB, int bsC, int bsBias) {
  __shared__ __align__(16) f16 As[64*40];
  __shared__ __align__(16) f16 Bs[128*40];
  int t = threadIdx.x;
  int m0 = blockIdx.x*64, n0 = blockIdx.y*128, z = blockIdx.z;
  A  += (size_t)z * bsA;
  BT += (size_t)z * bsB;
  if constexpr (MODE == 1) C += (size_t)z * bsC;
  else { Ch += (size_t)z * bsC; bias += (size_t)z * bsBias; }
  int lane = t & 63, wv = t >> 6, wm = wv >> 1, wn = wv & 1;
  int lr = lane & 15, lk = (lane >> 4) * 8;
  int arow = t >> 2, aseg = (t & 3) * 8;
  f32x4 acc[2][4] = {};
  for (int k0 = 0; k0 < K; k0 += 32) {
    __syncthreads();
    *(f16x8*)(&As[arow*40 + aseg]) = *(const f16x8*)(A + (size_t)(m0 + arow)*lda + k0 + aseg);
    *(f16x8*)(&Bs[arow*40 + aseg]) = *(const f16x8*)(BT + (size_t)(n0 + arow)*ldb + k0 + aseg);
    *(f16x8*)(&Bs[(64+arow)*40 + aseg]) = *(const f16x8*)(BT + (size_t)(n0 + 64 + arow)*ldb + k0 + aseg);
    __syncthreads();
    f16x8 af[2], bf[4];
    #pragma unroll
    for (int i = 0; i < 2; i++) af[i] = *(const f16x8*)(&As[(wm*32 + i*16 + lr)*40 + lk]);
    #pragma unroll
    for (int j = 0; j < 4; j++) bf[j] = *(const f16x8*)(&Bs[(wn*64 + j*16 + lr)*40 + lk]);
    #pragma unroll
    for (int i = 0; i < 2; i++)
      #pragma unroll
      for (int j = 0; j < 4; j++)
        acc[i][j] = __builtin_amdgcn_mfma_f32_16x16x32_f16(af[i], bf[j], acc[i][j], 0, 0, 0);
  }
  #pragma unroll
  for (int i = 0; i < 2; i++)
    #pragma unroll
    for (int j = 0; j < 4; j++)
      #pragma unroll
      for (int v = 0; v < 4; v++) {
        int r = m0 + wm*32 + i*16 + (lane >> 4)*4 + v;
        int cc = n0 + wn*64 + j*16 + lr;
        float val = acc[i][j][v];
        if constexpr (MODE == 1) {
          C[(size_t)r*N + cc] = val;
        } else {
          val += bias[cc];
          val = fmaxf(val, 0.f);
          Ch[(size_t)r*N + cc] = (f16)val;
        }
      }
}

// ---------------- head tail ----------------

__global__ __launch_bounds__(256) void k_mix(const f16* __restrict__ h2,
    const float* __restrict__ w3, const float* __restrict__ b3, float* __restrict__ mix) {
  int b = blockIdx.x, t = threadIdx.x;
  int wv = t >> 6, lane = t & 63;
  int rid = b*4 + wv;
  int m = rid >> 10, row = rid & 1023;
  const f16* hr = h2 + (size_t)(m*1024 + row)*DD;
  const float* w = w3 + m*DD;
  float s = 0.f;
  #pragma unroll
  for (int q = 0; q < 4; q++) { int d = lane + q*64; s += (float)hr[d] * w[d]; }
  #pragma unroll
  for (int o = 32; o; o >>= 1) s += __shfl_down(s, o, 64);
  if (lane == 0) mix[m*1024 + row] = s + b3[m];
}

__global__ __launch_bounds__(256) void k_out(const float* __restrict__ mix, float* __restrict__ out) {
  int i = blockIdx.x*256 + threadIdx.x;
  float v[10]; float mu = 0.f;
  #pragma unroll
  for (int m = 0; m < 10; m++) { v[m] = mix[m*1024 + i]; mu += v[m]; }
  mu *= 0.1f;
  float var = 0.f;
  #pragma unroll
  for (int m = 0; m < 10; m++) { float d = v[m] - mu; var += d*d; }
  var *= (1.f/9.f);
  out[i] = mu;
  out[1024 + i] = sqrtf(var + 1e-5f);
}

// ---------------- launch ----------------

extern "C" void kernel_launch(void* const* d_in, const int* in_sizes, int n_in,
                              void* d_out, int out_size, void* d_ws, size_t ws_size,
                              hipStream_t stream) {
  const float* x         = (const float*)d_in[0];
  const float* edge_attr = (const float*)d_in[1];
  const int*   edge_idx  = (const int*)  d_in[2];
  const float* lin_w     = (const float*)d_in[3];
  const float* lin_b     = (const float*)d_in[4];
  const float* bn_g      = (const float*)d_in[5];
  const float* bn_b      = (const float*)d_in[6];
  const float* nn_w1     = (const float*)d_in[7];
  const float* nn_b1     = (const float*)d_in[8];
  const float* nn_w2     = (const float*)d_in[9];
  const float* nn_b2     = (const float*)d_in[10];
  const float* root_w    = (const float*)d_in[11];
  const float* conv_b    = (const float*)d_in[12];
  const float* gru_wih   = (const float*)d_in[13];
  const float* gru_whh   = (const float*)d_in[14];
  const float* gru_bih   = (const float*)d_in[15];
  const float* gru_bhh   = (const float*)d_in[16];
  const float* mlp_w1    = (const float*)d_in[17];
  const float* mlp_b1    = (const float*)d_in[18];
  const float* mlp_w2    = (const float*)d_in[19];
  const float* mlp_b2    = (const float*)d_in[20];
  const float* mlp_w3    = (const float*)d_in[21];
  const float* mlp_b3    = (const float*)d_in[22];
  float* out = (float*)d_out;

  char* w = (char*)d_ws;
  size_t o = 0;
  auto nxt = [&](size_t b) -> size_t { size_t r = o; o += (b + 255) & ~(size_t)255; return r; };
  float* y      = (float*)(w + nxt(1048576));
  float* colsum = (float*)(w + nxt(1024));
  float* colsq  = (float*)(w + nxt(1024));
  float* xh     = (float*)(w + nxt(1048576));
  float* h      = (float*)(w + nxt(1048576));
  f16*   xc16   = (f16*)  (w + nxt(524288));
  f16*   h16e   = (f16*)  (w + nxt(524288));
  int*   cntAll = (int*)  (w + nxt(4096));
  int*   offAll = (int*)  (w + nxt(8192));
  float* denomB = (float*)(w + nxt(4096));
  unsigned* rec = (unsigned*)(w + nxt(8192));
  int*   srcD   = (int*)  (w + nxt(8192));
  f16*   BTb    = (f16*)  (w + nxt((size_t)32768*256*2));       // 16.8 MB
  f16*   Bside  = (f16*)  (w + nxt((size_t)512*256*2));         // 256 KB
  float* T2R    = (float*)(w + nxt((size_t)1024*512*4));        // 2 MB
  float* msgbuf = (float*)(w + nxt((size_t)EE*256*4));          // 2 MB
  f16*   Am     = (f16*)  (w + nxt(524288));                    // [1024][256] conv output
  float* G2     = (float*)(w + nxt((size_t)1024*768*4));        // gh
  f16*   Wb     = (f16*)  (w + nxt(786432));                    // wih | whh  [768][256] each
  f16*   w1T    = (f16*)  (w + nxt(1310720));
  f16*   w2T    = (f16*)  (w + nxt(1310720));
  f16*   h1     = (f16*)  (w + nxt(5242880));
  f16*   h2     = (f16*)  (w + nxt(5242880));
  float* mixb   = (float*)(w + nxt(40960));
  if (o > ws_size) return;

  hipMemsetAsync(colsum, 0, 2048, stream);   // colsum + colsq contiguous

  k_embed_hidden<<<1280, 256, 0, stream>>>(x, lin_w, lin_b, edge_attr, nn_w1, nn_b1,
                                           y, colsum, colsq, h16e);
  k_csrbn<<<257, 1024, 0, stream>>>(edge_idx, cntAll, offAll, denomB, rec, srcD,
                                    y, colsum, colsq, bn_g, bn_b, xh, xc16);
  k_prep<<<2244, 256, 0, stream>>>(nn_w2, BTb, gru_wih, Wb, gru_whh, Wb + 196608,
                                   mlp_w1, w1T, mlp_w2, w2T, root_w, nn_b2, Bside);

  for (int it = 0; it < 3; it++) {
    const float* hOld = (it == 0) ? xh : h;
    k_fgemm<<<4352, 256, 0, stream>>>(xc16, BTb, Bside, Wb + 196608, h16e, offAll,
                                      rec, T2R, G2, msgbuf);
    k_fin  <<<1024, 256, 0, stream>>>(msgbuf, cntAll, offAll, denomB, T2R, srcD, conv_b, Am);
    k_gru  <<<dim3(32, 4), 256, 0, stream>>>(Am, Wb, G2, gru_bih, gru_bhh, hOld, h, xc16);
  }

  k_gemm_sm<3><<<dim3(16, 2, 10), 256, 0, stream>>>(xc16, w1T, nullptr, h1, mlp_b1,
      256, 256, 256, 256, 0, 65536, 262144, 256);
  k_gemm_sm<3><<<dim3(16, 2, 10), 256, 0, stream>>>(h1, w2T, nullptr, h2, mlp_b2,
      256, 256, 256, 256, 262144, 65536, 262144, 256);
  k_mix<<<2560, 256, 0, stream>>>(h2, mlp_w3, mlp_b3, mixb);
  k_out<<<4, 256, 0, stream>>>(mixb, out);
}

// Round 17
// 229.765 us; speedup vs baseline: 1.0153x; 1.0153x over previous
//
#include <hip/hip_runtime.h>
#include <hip/hip_bf16.h>
#include <math.h>

typedef _Float16 f16;
typedef _Float16 f16x8 __attribute__((ext_vector_type(8)));
typedef _Float16 f16x4 __attribute__((ext_vector_type(4)));
typedef _Float16 f16x2 __attribute__((ext_vector_type(2)));
typedef _Float16 half2v __attribute__((ext_vector_type(2)));
typedef float    f32x4 __attribute__((ext_vector_type(4)));

#define NN 1024
#define EE 2048
#define DD 256
#define EDH 128

typedef const __attribute__((address_space(1))) void gas_t;
typedef __attribute__((address_space(3))) void las_t;
#define GLOAD16(g, l) __builtin_amdgcn_global_load_lds((gas_t*)(g), (las_t*)(l), 16, 0, 0)

#if __has_builtin(__builtin_amdgcn_fdot2)
#define DOT2(a, b, c) __builtin_amdgcn_fdot2((a), (b), (c), false)
#else
#define DOT2(a, b, c) ((float)(a)[0]*(float)(b)[0] + (float)(a)[1]*(float)(b)[1] + (c))
#endif

// ---------------- prep: embed (4 nodes/block, +bn stats) fused with edge-MLP ----------------

__global__ __launch_bounds__(256) void k_embed_hidden(const float* __restrict__ x,
    const float* __restrict__ lw, const float* __restrict__ lb,
    const float* __restrict__ ea, const float* __restrict__ w1, const float* __restrict__ b1,
    float* __restrict__ y, float* __restrict__ colsum, float* __restrict__ colsq,
    f16* __restrict__ h16e) {
  int bid = blockIdx.x, t = threadIdx.x;
  if (bid < 256) {
    int n0 = bid*4;
    __shared__ float xr[4][38];
    if (t < 152) ((float*)xr)[t] = x[n0*38 + t];
    __syncthreads();
    float b0 = lb[t];
    float s0 = b0, s1 = b0, s2 = b0, s3 = b0;
    const float* w = lw + t*38;
    #pragma unroll
    for (int d = 0; d < 38; d++) {
      float wd = w[d];
      s0 += xr[0][d]*wd; s1 += xr[1][d]*wd; s2 += xr[2][d]*wd; s3 += xr[3][d]*wd;
    }
    y[(n0+0)*DD + t] = s0; y[(n0+1)*DD + t] = s1;
    y[(n0+2)*DD + t] = s2; y[(n0+3)*DD + t] = s3;
    atomicAdd(&colsum[t], s0+s1+s2+s3);
    atomicAdd(&colsq[t], s0*s0+s1*s1+s2*s2+s3*s3);
  } else {
    int e = (bid - 256)*2 + (t >> 7);
    int k = t & 127;
    const float* a = ea + e*4;
    const float* w = w1 + k*4;
    float s = b1[k] + a[0]*w[0] + a[1]*w[1] + a[2]*w[2] + a[3]*w[3];
    h16e[e*EDH + k] = (f16)(1.f / (1.f + expf(-s)));
  }
}

// ---------------- merged: CSR build (block 0, wave-scan) + bn-normalize (blocks 1..256) --------

__global__ __launch_bounds__(1024) void k_csrbn(const int* __restrict__ ei,
    int* __restrict__ cntAll, int* __restrict__ offAll, float* __restrict__ denomB,
    unsigned* __restrict__ rec, int* __restrict__ srcD,
    const float* __restrict__ y, const float* __restrict__ colsum,
    const float* __restrict__ colsq, const float* __restrict__ g, const float* __restrict__ b,
    float* __restrict__ xh, f16* __restrict__ xc16) {
  int bid = blockIdx.x, t = threadIdx.x;
  if (bid > 0) {                       // bn apply: 256 blocks x 1024 elems
    int i = (bid - 1)*1024 + t;
    int c = i & 255;
    float mean = colsum[c] * (1.f/1024.f);
    float var  = colsq[c] * (1.f/1024.f) - mean*mean;
    float sc = g[c] / sqrtf(var + 1e-5f);
    float sh = b[c] - mean*sc;
    float v = y[i]*sc + sh;
    xh[i] = v;
    xc16[i] = (f16)v;
    return;
  }
  // block 0: CSR build with wave-level scans
  __shared__ int cntD[1024], cntS[1024], curD[1024], curS[1024];
  __shared__ int wsD[16], wsS[16];
  cntD[t] = 0; cntS[t] = 0;
  __syncthreads();
  int e0 = t, e1 = 1024 + t;
  int d0 = ei[EE + e0], s0 = ei[e0];
  int d1 = ei[EE + e1], s1 = ei[e1];
  atomicAdd(&cntD[d0], 1); atomicAdd(&cntS[s0], 1);
  atomicAdd(&cntD[d1], 1); atomicAdd(&cntS[s1], 1);
  __syncthreads();
  int cD = cntD[t], cS = cntS[t];
  int lane = t & 63, wid = t >> 6;
  int iD = cD, iS = cS;                // wave-inclusive scans
  #pragma unroll
  for (int o = 1; o < 64; o <<= 1) {
    int uD = __shfl_up(iD, o, 64);
    int uS = __shfl_up(iS, o, 64);
    if (lane >= o) { iD += uD; iS += uS; }
  }
  if (lane == 63) { wsD[wid] = iD; wsS[wid] = iS; }
  __syncthreads();
  if (t < 16) {
    int vD = wsD[t], vS = wsS[t];
    #pragma unroll
    for (int o = 1; o < 16; o <<= 1) {
      int uD = __shfl_up(vD, o, 64);
      int uS = __shfl_up(vS, o, 64);
      if (t >= o) { vD += uD; vS += uS; }
    }
    wsD[t] = vD; wsS[t] = vS;
  }
  __syncthreads();
  int exD = (wid ? wsD[wid-1] : 0) + iD - cD;
  int exS = (wid ? wsS[wid-1] : 0) + iS - cS;
  curD[t] = exD; curS[t] = exS;
  cntAll[t] = cD; offAll[t] = exD;
  offAll[1024 + t] = exS;
  denomB[t] = (float)(cD > 1 ? cD : 1);
  __syncthreads();
  int pD = atomicAdd(&curD[d0], 1);
  int pS = atomicAdd(&curS[s0], 1);
  rec[pS] = (unsigned)e0 | ((unsigned)s0 << 11) | ((unsigned)pD << 21);
  srcD[pD] = s0;
  pD = atomicAdd(&curD[d1], 1);
  pS = atomicAdd(&curS[s1], 1);
  rec[pS] = (unsigned)e1 | ((unsigned)s1 << 11) | ((unsigned)pD << 21);
  srcD[pD] = s1;
}

// ---------------- merged weight prep: w2 transpose + all casts + Bside build ----------------

__global__ __launch_bounds__(256) void k_prep(const float* __restrict__ w2, f16* __restrict__ BTb,
    const float* __restrict__ s0, f16* __restrict__ d0,
    const float* __restrict__ s1, f16* __restrict__ d1,
    const float* __restrict__ s2, f16* __restrict__ d2,
    const float* __restrict__ s3, f16* __restrict__ d3,
    const float* __restrict__ rw, const float* __restrict__ nb2, f16* __restrict__ Bside) {
  __shared__ __align__(16) char shm[33280];
  int bid = blockIdx.x, t = threadIdx.x;
  if (bid < 512) {                     // w2 transpose
    f16 (*ls)[130] = (f16(*)[130])shm;
    int f = bid & 255, dh = bid >> 8;
    int dl = t >> 1, kh = (t & 1) * 64;
    const float* src = w2 + ((size_t)(dh*128 + dl)*256 + f)*128 + kh;
    #pragma unroll
    for (int i = 0; i < 16; i++) {
      f32x4 v = *(const f32x4*)(src + i*4);
      f16x2 a = {(f16)v[0], (f16)v[1]};
      f16x2 bb = {(f16)v[2], (f16)v[3]};
      *(f16x2*)(&ls[dl][kh + i*4])     = a;
      *(f16x2*)(&ls[dl][kh + i*4 + 2]) = bb;
    }
    __syncthreads();
    int k = t >> 1, dh2 = (t & 1) * 64;
    f16* dst = BTb + ((size_t)f*128 + k)*256 + dh*128 + dh2;
    #pragma unroll
    for (int gq = 0; gq < 8; gq++) {
      f16x8 pk;
      #pragma unroll
      for (int q = 0; q < 8; q++) pk[q] = ls[dh2 + gq*8 + q][k];
      *(f16x8*)(dst + gq*8) = pk;
    }
  } else if (bid < 2176) {             // casts
    int cb = bid - 512;
    const float* src; f16* dst; int i;
    if      (cb < 192)  { src = s0; dst = d0; i = cb*256 + t; }
    else if (cb < 384)  { src = s1; dst = d1; i = (cb-192)*256 + t; }
    else if (cb < 1024) { src = s2; dst = d2; i = (cb-384)*256 + t; }
    else                { src = s3; dst = d3; i = (cb-1024)*256 + t; }
    f32x4 v = ((const f32x4*)src)[i];
    f16x4 r; r[0]=(f16)v[0]; r[1]=(f16)v[1]; r[2]=(f16)v[2]; r[3]=(f16)v[3];
    ((f16x4*)dst)[i] = r;
  } else if (bid < 2240) {             // root linear
    int i = (bid - 2176)*256 + t;
    f32x4 v = *(const f32x4*)(rw + (size_t)i*4);
    f16x4 r; r[0]=(f16)v[0]; r[1]=(f16)v[1]; r[2]=(f16)v[2]; r[3]=(f16)v[3];
    *(f16x4*)(Bside + 65536 + (size_t)i*4) = r;
  } else {                             // b2 transpose
    float (*ls)[65] = (float(*)[65])shm;
    int fb = bid - 2240;
    for (int db = 0; db < 4; db++) {
      int r = t >> 2, cs = (t & 3) * 16;
      const float* s = nb2 + (size_t)(db*64 + r)*256 + fb*64 + cs;
      #pragma unroll
      for (int i = 0; i < 16; i += 4) {
        f32x4 v = *(const f32x4*)(s + i);
        ls[r][cs+i] = v[0]; ls[r][cs+i+1] = v[1]; ls[r][cs+i+2] = v[2]; ls[r][cs+i+3] = v[3];
      }
      __syncthreads();
      int fl = t >> 2, ds2 = (t & 3) * 16;
      f16x8 p0, p1;
      #pragma unroll
      for (int q = 0; q < 8; q++) { p0[q] = (f16)ls[ds2+q][fl]; p1[q] = (f16)ls[ds2+8+q][fl]; }
      f16* d = Bside + (size_t)(fb*64 + fl)*256 + db*64 + ds2;
      *(f16x8*)(d)     = p0;
      *(f16x8*)(d + 8) = p1;
      __syncthreads();
    }
  }
}

// ---------------- fused conv GEMM (64x128 tile, BK=64, high-occupancy) + edge epilogue ---------
// p <  256 : T-panel for f=p; epilogue -> msgbuf[pos][p]
// p in [256,260): side GEMM vs Bside -> T2R raw f32 (b2 | root columns)
// p in [260,266): gh GEMM vs whh -> G2 raw f32 (gh = xc16 @ whh^T)

__global__ __launch_bounds__(256) void k_fgemm(const f16* __restrict__ A,
    const f16* __restrict__ BTb, const f16* __restrict__ Bside, const f16* __restrict__ Wbh,
    const f16* __restrict__ h16e, const int* __restrict__ offAll,
    const unsigned* __restrict__ rec, float* __restrict__ T2R,
    float* __restrict__ G2, float* __restrict__ msgbuf) {
  __shared__ __align__(16) f16 lds[12288];   // 24KB: As 4096 + Bs 8192; tile 64x128 (8192) aliases
  int raw = blockIdx.x;
  int pmod = raw & 7, q = raw >> 3;
  int m = q & 15, pg = q >> 4;
  int p = pg*8 + pmod;                 // same p%8 -> same XCD: panel L2-shared by 16 m-blocks
  if (p >= 266) return;
  int m0 = m*64;
  int t = threadIdx.x;
  int lane = t & 63, wv = t >> 6, wm = wv >> 1, wn = wv & 1;
  int lr = lane & 15, lg = lane >> 4;
  const f16* Bbase = (p < 256) ? (BTb + (size_t)p*32768)
                   : (p < 260) ? (Bside + (size_t)(p-256)*32768)
                               : (Wbh + (size_t)(p-260)*32768);
  // A staging: sub-panel 64x32 = 2048 f16; wave wv covers [wv*512, +512)
  int ea = wv*512 + lane*8;
  int ra = ea >> 5, ca = ea & 31;
  const f16* AgA = A + (size_t)(m0 + ra)*256 + ca;
  // B staging: sub-panel 128x32 = 4096 f16; wave wv covers [wv*1024, +1024) via 2 instrs
  int e0 = wv*1024 + lane*8;
  int r0 = e0 >> 5, c0 = e0 & 31;
  int e1 = e0 + 512;
  int r1 = e1 >> 5, c1 = e1 & 31;
  const f16* Bg0 = Bbase + (size_t)r0*256 + c0;
  const f16* Bg1 = Bbase + (size_t)r1*256 + c1;
  f16* As = lds;                 // sub-panels at +0, +2048
  f16* Bs = lds + 4096;          // sub-panels at +0, +4096
  f16* AlA = As + wv*512;
  f16* Bl0 = Bs + wv*1024; f16* Bl1 = Bl0 + 512;
  f32x4 acc[2][4] = {};
  for (int k0 = 0; k0 < 256; k0 += 64) {
    __syncthreads();
    GLOAD16(AgA + k0,      AlA);
    GLOAD16(AgA + k0 + 32, AlA + 2048);
    GLOAD16(Bg0 + k0,      Bl0);
    GLOAD16(Bg1 + k0,      Bl1);
    GLOAD16(Bg0 + k0 + 32, Bl0 + 4096);
    GLOAD16(Bg1 + k0 + 32, Bl1 + 4096);
    __syncthreads();
    #pragma unroll
    for (int P = 0; P < 2; P++) {
      f16x8 af[2], bf[4];
      #pragma unroll
      for (int i = 0; i < 2; i++)
        af[i] = *(const f16x8*)(&As[P*2048 + (wm*32 + i*16 + lr)*32 + lg*8]);
      #pragma unroll
      for (int j = 0; j < 4; j++)
        bf[j] = *(const f16x8*)(&Bs[P*4096 + (wn*64 + j*16 + lr)*32 + lg*8]);
      #pragma unroll
      for (int i = 0; i < 2; i++)
        #pragma unroll
        for (int j = 0; j < 4; j++)
          acc[i][j] = __builtin_amdgcn_mfma_f32_16x16x32_f16(af[i], bf[j], acc[i][j], 0, 0, 0);
    }
  }
  if (p >= 260) {                      // gh panel: raw f32 to G2[1024][768]
    int c0o = (p - 260)*128;
    #pragma unroll
    for (int i = 0; i < 2; i++)
      #pragma unroll
      for (int j = 0; j < 4; j++)
        #pragma unroll
        for (int v = 0; v < 4; v++)
          G2[(size_t)(m0 + wm*32 + i*16 + lg*4 + v)*768 + c0o + wn*64 + j*16 + lr] = acc[i][j][v];
    return;
  }
  if (p >= 256) {                      // side panel: raw f32 to T2R[1024][512]
    int c0o = (p - 256)*128;
    #pragma unroll
    for (int i = 0; i < 2; i++)
      #pragma unroll
      for (int j = 0; j < 4; j++)
        #pragma unroll
        for (int v = 0; v < 4; v++)
          T2R[(size_t)(m0 + wm*32 + i*16 + lg*4 + v)*512 + c0o + wn*64 + j*16 + lr] = acc[i][j][v];
    return;
  }
  __syncthreads();                     // staging reads done; swizzled tile aliases staging
  #pragma unroll
  for (int i = 0; i < 2; i++)
    #pragma unroll
    for (int j = 0; j < 4; j++)
      #pragma unroll
      for (int v = 0; v < 4; v++) {
        int r = wm*32 + i*16 + lg*4 + v;
        int c = wn*64 + j*16 + lr;
        lds[r*128 + (((c >> 3) ^ (r & 7)) << 3) + (c & 7)] = (f16)acc[i][j][v];
      }
  __syncthreads();
  int eS = offAll[1024 + m0];
  int eE = (m0 + 64 < 1024) ? offAll[1024 + m0 + 64] : EE;
  int g = t & 1, es = t >> 1;          // 2 lanes per edge (g = which 64-elem half)
  for (int idx = eS + es; idx < eE; idx += 128) {
    unsigned u = rec[idx];
    int e = u & 2047, src = (u >> 11) & 1023, pos = (int)(u >> 21);
    int r = src - m0;
    const f16* hp = h16e + (size_t)e*EDH + g*64;
    float s0 = 0.f, s1 = 0.f;
    #pragma unroll
    for (int i = 0; i < 8; i++) {
      int blk = g*8 + i;
      f16x8 hv = *(const f16x8*)(hp + i*8);
      f16x8 tv = *(const f16x8*)(&lds[r*128 + ((blk ^ (r & 7)) << 3)]);
      union { f16x8 v8; half2v pr[4]; } hu, tu;
      hu.v8 = hv; tu.v8 = tv;
      float sx = (i & 1) ? s1 : s0;
      #pragma unroll
      for (int qd = 0; qd < 4; qd++) sx = DOT2(hu.pr[qd], tu.pr[qd], sx);
      if (i & 1) s1 = sx; else s0 = sx;
    }
    float s = s0 + s1;
    s += __shfl_xor(s, 1, 64);
    if (g == 0) msgbuf[(size_t)pos*256 + p] = s;
  }
}

// ---------------- fin: segment-sum msgbuf + per-edge b2 term, /denom, +root+bias, relu ----------

__global__ __launch_bounds__(256) void k_fin(const float* __restrict__ msgbuf,
    const int* __restrict__ cntAll, const int* __restrict__ offAll,
    const float* __restrict__ denomB, const float* __restrict__ T2R,
    const int* __restrict__ srcD, const float* __restrict__ cb, f16* __restrict__ Am) {
  int n = blockIdx.x, t = threadIdx.x;
  int deg = cntAll[n], o = offAll[n];
  float s = 0.f;
  for (int j = 0; j < deg; j++)
    s += msgbuf[(size_t)(o+j)*256 + t] + T2R[(size_t)srcD[o+j]*512 + t];
  float m = s / denomB[n] + T2R[(size_t)n*512 + 256 + t] + cb[t];
  Am[(size_t)n*256 + t] = (f16)fmaxf(m, 0.f);
}

// ---------------- gi GEMM: 64x64 tile (192 WGs), f32 store ----------------

__global__ __launch_bounds__(256) void k_gemm64(const f16* __restrict__ A,
    const f16* __restrict__ BT, float* __restrict__ C) {
  __shared__ __align__(16) f16 As[64*40];
  __shared__ __align__(16) f16 Bs[64*40];
  int t = threadIdx.x;
  int m0 = blockIdx.x*64, n0 = blockIdx.y*64;
  int lane = t & 63, wv = t >> 6, wm = wv >> 1, wn = wv & 1;
  int lr = lane & 15, lk = (lane >> 4) * 8;
  int arow = t >> 2, aseg = (t & 3) * 8;
  f32x4 acc[2][2] = {};
  for (int k0 = 0; k0 < 256; k0 += 32) {
    __syncthreads();
    *(f16x8*)(&As[arow*40 + aseg]) = *(const f16x8*)(A + (size_t)(m0 + arow)*256 + k0 + aseg);
    *(f16x8*)(&Bs[arow*40 + aseg]) = *(const f16x8*)(BT + (size_t)(n0 + arow)*256 + k0 + aseg);
    __syncthreads();
    f16x8 af[2], bf[2];
    #pragma unroll
    for (int i = 0; i < 2; i++) af[i] = *(const f16x8*)(&As[(wm*32 + i*16 + lr)*40 + lk]);
    #pragma unroll
    for (int j = 0; j < 2; j++) bf[j] = *(const f16x8*)(&Bs[(wn*32 + j*16 + lr)*40 + lk]);
    #pragma unroll
    for (int i = 0; i < 2; i++)
      #pragma unroll
      for (int j = 0; j < 2; j++)
        acc[i][j] = __builtin_amdgcn_mfma_f32_16x16x32_f16(af[i], bf[j], acc[i][j], 0, 0, 0);
  }
  #pragma unroll
  for (int i = 0; i < 2; i++)
    #pragma unroll
    for (int j = 0; j < 2; j++)
      #pragma unroll
      for (int v = 0; v < 4; v++) {
        int r = m0 + wm*32 + i*16 + (lane >> 4)*4 + v;
        int cc = n0 + wn*32 + j*16 + lr;
        C[(size_t)r*768 + cc] = acc[i][j][v];
      }
}

// ---------------- small GEMM: 64x128 tile. MODE 1: f32 store; MODE 3: bias+relu f16 ----------------

template<int MODE>
__global__ __launch_bounds__(256) void k_gemm_sm(const f16* __restrict__ A,
    const f16* __restrict__ BT, float* __restrict__ C, f16* __restrict__ Ch,
    const float* __restrict__ bias, int K, int lda, int ldb, int N,
    int bsA, int bsB, int bsC, int bsBias) {
  __shared__ __align__(16) f16 As[64*40];
  __shared__ __align__(16) f16 Bs[128*40];
  int t = threadIdx.x;
  int m0 = blockIdx.x*64, n0 = blockIdx.y*128, z = blockIdx.z;
  A  += (size_t)z * bsA;
  BT += (size_t)z * bsB;
  if constexpr (MODE == 1) C += (size_t)z * bsC;
  else { Ch += (size_t)z * bsC; bias += (size_t)z * bsBias; }
  int lane = t & 63, wv = t >> 6, wm = wv >> 1, wn = wv & 1;
  int lr = lane & 15, lk = (lane >> 4) * 8;
  int arow = t >> 2, aseg = (t & 3) * 8;
  f32x4 acc[2][4] = {};
  for (int k0 = 0; k0 < K; k0 += 32) {
    __syncthreads();
    *(f16x8*)(&As[arow*40 + aseg]) = *(const f16x8*)(A + (size_t)(m0 + arow)*lda + k0 + aseg);
    *(f16x8*)(&Bs[arow*40 + aseg]) = *(const f16x8*)(BT + (size_t)(n0 + arow)*ldb + k0 + aseg);
    *(f16x8*)(&Bs[(64+arow)*40 + aseg]) = *(const f16x8*)(BT + (size_t)(n0 + 64 + arow)*ldb + k0 + aseg);
    __syncthreads();
    f16x8 af[2], bf[4];
    #pragma unroll
    for (int i = 0; i < 2; i++) af[i] = *(const f16x8*)(&As[(wm*32 + i*16 + lr)*40 + lk]);
    #pragma unroll
    for (int j = 0; j < 4; j++) bf[j] = *(const f16x8*)(&Bs[(wn*64 + j*16 + lr)*40 + lk]);
    #pragma unroll
    for (int i = 0; i < 2; i++)
      #pragma unroll
      for (int j = 0; j < 4; j++)
        acc[i][j] = __builtin_amdgcn_mfma_f32_16x16x32_f16(af[i], bf[j], acc[i][j], 0, 0, 0);
  }
  #pragma unroll
  for (int i = 0; i < 2; i++)
    #pragma unroll
    for (int j = 0; j < 4; j++)
      #pragma unroll
      for (int v = 0; v < 4; v++) {
        int r = m0 + wm*32 + i*16 + (lane >> 4)*4 + v;
        int cc = n0 + wn*64 + j*16 + lr;
        float val = acc[i][j][v];
        if constexpr (MODE == 1) {
          C[(size_t)r*N + cc] = val;
        } else {
          val += bias[cc];
          val = fmaxf(val, 0.f);
          Ch[(size_t)r*N + cc] = (f16)val;
        }
      }
}

// ---------------- GRU gates ----------------

__global__ __launch_bounds__(256) void k_gate(const float* __restrict__ gi,
    const float* __restrict__ gh, const float* __restrict__ bih, const float* __restrict__ bhh,
    const float* __restrict__ hOld, float* __restrict__ hNew, f16* __restrict__ xc16) {
  int i = blockIdx.x*256 + threadIdx.x;
  int row = i >> 8, c = i & 255;
  const float* gir = gi + (size_t)row*768;
  const float* ghr = gh + (size_t)row*768;
  float ir  = gir[c]     + bih[c],     hr = ghr[c]     + bhh[c];
  float iz  = gir[256+c] + bih[256+c], hz = ghr[256+c] + bhh[256+c];
  float inn = gir[512+c] + bih[512+c], hn = ghr[512+c] + bhh[512+c];
  float r  = 1.f / (1.f + expf(-(ir + hr)));
  float zz = 1.f / (1.f + expf(-(iz + hz)));
  float nn = tanhf(inn + r*hn);
  float hv = (1.f - zz)*nn + zz*hOld[i];
  hNew[i] = hv;
  xc16[i] = (f16)hv;
}

// ---------------- head tail ----------------

__global__ __launch_bounds__(256) void k_mix(const f16* __restrict__ h2,
    const float* __restrict__ w3, const float* __restrict__ b3, float* __restrict__ mix) {
  int b = blockIdx.x, t = threadIdx.x;
  int wv = t >> 6, lane = t & 63;
  int rid = b*4 + wv;
  int m = rid >> 10, row = rid & 1023;
  const f16* hr = h2 + (size_t)(m*1024 + row)*DD;
  const float* w = w3 + m*DD;
  float s = 0.f;
  #pragma unroll
  for (int q = 0; q < 4; q++) { int d = lane + q*64; s += (float)hr[d] * w[d]; }
  #pragma unroll
  for (int o = 32; o; o >>= 1) s += __shfl_down(s, o, 64);
  if (lane == 0) mix[m*1024 + row] = s + b3[m];
}

__global__ __launch_bounds__(256) void k_out(const float* __restrict__ mix, float* __restrict__ out) {
  int i = blockIdx.x*256 + threadIdx.x;
  float v[10]; float mu = 0.f;
  #pragma unroll
  for (int m = 0; m < 10; m++) { v[m] = mix[m*1024 + i]; mu += v[m]; }
  mu *= 0.1f;
  float var = 0.f;
  #pragma unroll
  for (int m = 0; m < 10; m++) { float d = v[m] - mu; var += d*d; }
  var *= (1.f/9.f);
  out[i] = mu;
  out[1024 + i] = sqrtf(var + 1e-5f);
}

// ---------------- launch ----------------

extern "C" void kernel_launch(void* const* d_in, const int* in_sizes, int n_in,
                              void* d_out, int out_size, void* d_ws, size_t ws_size,
                              hipStream_t stream) {
  const float* x         = (const float*)d_in[0];
  const float* edge_attr = (const float*)d_in[1];
  const int*   edge_idx  = (const int*)  d_in[2];
  const float* lin_w     = (const float*)d_in[3];
  const float* lin_b     = (const float*)d_in[4];
  const float* bn_g      = (const float*)d_in[5];
  const float* bn_b      = (const float*)d_in[6];
  const float* nn_w1     = (const float*)d_in[7];
  const float* nn_b1     = (const float*)d_in[8];
  const float* nn_w2     = (const float*)d_in[9];
  const float* nn_b2     = (const float*)d_in[10];
  const float* root_w    = (const float*)d_in[11];
  const float* conv_b    = (const float*)d_in[12];
  const float* gru_wih   = (const float*)d_in[13];
  const float* gru_whh   = (const float*)d_in[14];
  const float* gru_bih   = (const float*)d_in[15];
  const float* gru_bhh   = (const float*)d_in[16];
  const float* mlp_w1    = (const float*)d_in[17];
  const float* mlp_b1    = (const float*)d_in[18];
  const float* mlp_w2    = (const float*)d_in[19];
  const float* mlp_b2    = (const float*)d_in[20];
  const float* mlp_w3    = (const float*)d_in[21];
  const float* mlp_b3    = (const float*)d_in[22];
  float* out = (float*)d_out;

  char* w = (char*)d_ws;
  size_t o = 0;
  auto nxt = [&](size_t b) -> size_t { size_t r = o; o += (b + 255) & ~(size_t)255; return r; };
  float* y      = (float*)(w + nxt(1048576));
  float* colsum = (float*)(w + nxt(1024));
  float* colsq  = (float*)(w + nxt(1024));
  float* xh     = (float*)(w + nxt(1048576));
  float* h      = (float*)(w + nxt(1048576));
  f16*   xc16   = (f16*)  (w + nxt(524288));
  f16*   h16e   = (f16*)  (w + nxt(524288));
  int*   cntAll = (int*)  (w + nxt(4096));
  int*   offAll = (int*)  (w + nxt(8192));
  float* denomB = (float*)(w + nxt(4096));
  unsigned* rec = (unsigned*)(w + nxt(8192));
  int*   srcD   = (int*)  (w + nxt(8192));
  f16*   BTb    = (f16*)  (w + nxt((size_t)32768*256*2));       // 16.8 MB
  f16*   Bside  = (f16*)  (w + nxt((size_t)512*256*2));         // 256 KB
  float* T2R    = (float*)(w + nxt((size_t)1024*512*4));        // 2 MB
  float* msgbuf = (float*)(w + nxt((size_t)EE*256*4));          // 2 MB
  f16*   Am     = (f16*)  (w + nxt(524288));                    // [1024][256] conv output
  float* G      = (float*)(w + nxt((size_t)2*1024*768*4));      // gi | gh
  f16*   Wb     = (f16*)  (w + nxt(786432));                    // wih | whh  [768][256] each
  f16*   w1T    = (f16*)  (w + nxt(1310720));
  f16*   w2T    = (f16*)  (w + nxt(1310720));
  f16*   h1     = (f16*)  (w + nxt(5242880));
  f16*   h2     = (f16*)  (w + nxt(5242880));
  float* mixb   = (float*)(w + nxt(40960));
  if (o > ws_size) return;

  hipMemsetAsync(colsum, 0, 2048, stream);   // colsum + colsq contiguous

  k_embed_hidden<<<1280, 256, 0, stream>>>(x, lin_w, lin_b, edge_attr, nn_w1, nn_b1,
                                           y, colsum, colsq, h16e);
  k_csrbn<<<257, 1024, 0, stream>>>(edge_idx, cntAll, offAll, denomB, rec, srcD,
                                    y, colsum, colsq, bn_g, bn_b, xh, xc16);
  k_prep<<<2244, 256, 0, stream>>>(nn_w2, BTb, gru_wih, Wb, gru_whh, Wb + 196608,
                                   mlp_w1, w1T, mlp_w2, w2T, root_w, nn_b2, Bside);

  for (int it = 0; it < 3; it++) {
    const float* hOld = (it == 0) ? xh : h;
    k_fgemm<<<4352, 256, 0, stream>>>(xc16, BTb, Bside, Wb + 196608, h16e, offAll,
                                      rec, T2R, G + 786432, msgbuf);
    k_fin  <<<1024, 256, 0, stream>>>(msgbuf, cntAll, offAll, denomB, T2R, srcD, conv_b, Am);
    k_gemm64<<<dim3(16, 12), 256, 0, stream>>>(Am, Wb, G);
    k_gate<<<1024, 256, 0, stream>>>(G, G + 786432, gru_bih, gru_bhh, hOld, h, xc16);
  }

  k_gemm_sm<3><<<dim3(16, 2, 10), 256, 0, stream>>>(xc16, w1T, nullptr, h1, mlp_b1,
      256, 256, 256, 256, 0, 65536, 262144, 256);
  k_gemm_sm<3><<<dim3(16, 2, 10), 256, 0, stream>>>(h1, w2T, nullptr, h2, mlp_b2,
      256, 256, 256, 256, 262144, 65536, 262144, 256);
  k_mix<<<2560, 256, 0, stream>>>(h2, mlp_w3, mlp_b3, mixb);
  k_out<<<4, 256, 0, stream>>>(mixb, out);
}